// Round 1
// baseline (446.588 us; speedup 1.0000x reference)
//
#include <hip/hip_runtime.h>

#define N       8192
#define F_IN    128
#define F_OUT   64
#define NEG_SLOPE 0.2f
#define VERY_SMALL 1.0e12f

// ---------------------------------------------------------------------------
// K0: ws[k] = sum_j w[k][j] * a[j]   ;  wd[k] = sum_j w[k][j] * a[F_OUT + j]
// one block, 128 threads (one per k)
// ---------------------------------------------------------------------------
__global__ void prep_kernel(const float* __restrict__ w, const float* __restrict__ a,
                            float* __restrict__ ws, float* __restrict__ wd) {
    int k = threadIdx.x;          // 0..127
    float s = 0.f, d = 0.f;
#pragma unroll
    for (int j = 0; j < F_OUT; ++j) {
        float wv = w[k * F_OUT + j];
        s += wv * a[j];
        d += wv * a[F_OUT + j];
    }
    ws[k] = s;
    wd[k] = d;
}

// ---------------------------------------------------------------------------
// K1: src[i] = dot(h[i,:], ws) ; dst[i] = dot(h[i,:], wd)
// grid N/256, block 256 — one row of h per thread, float4 loads
// ---------------------------------------------------------------------------
__global__ void srcdst_kernel(const float* __restrict__ h, const float* __restrict__ ws,
                              const float* __restrict__ wd,
                              float* __restrict__ src, float* __restrict__ dst) {
    __shared__ float sws[F_IN], swd[F_IN];
    int t = threadIdx.x;
    if (t < F_IN) { sws[t] = ws[t]; swd[t] = wd[t]; }
    __syncthreads();
    int i = blockIdx.x * blockDim.x + t;
    const float4* h4 = reinterpret_cast<const float4*>(h + (size_t)i * F_IN);
    float s = 0.f, d = 0.f;
#pragma unroll
    for (int k4 = 0; k4 < F_IN / 4; ++k4) {
        float4 hv = h4[k4];
        s += hv.x * sws[k4*4+0] + hv.y * sws[k4*4+1] + hv.z * sws[k4*4+2] + hv.w * sws[k4*4+3];
        d += hv.x * swd[k4*4+0] + hv.y * swd[k4*4+1] + hv.z * swd[k4*4+2] + hv.w * swd[k4*4+3];
    }
    src[i] = s;
    dst[i] = d;
}

// ---------------------------------------------------------------------------
// K2: per-row masked softmax, one row per block.
// 256 threads x 32 elements (8 x float4). Logits kept in registers.
// ---------------------------------------------------------------------------
__device__ __forceinline__ float waveReduceMax(float x) {
#pragma unroll
    for (int off = 32; off > 0; off >>= 1) x = fmaxf(x, __shfl_xor(x, off));
    return x;
}
__device__ __forceinline__ float waveReduceSum(float x) {
#pragma unroll
    for (int off = 32; off > 0; off >>= 1) x += __shfl_xor(x, off);
    return x;
}

__global__ __launch_bounds__(256) void row_softmax_kernel(
        const float* __restrict__ adj, const float* __restrict__ src,
        const float* __restrict__ dst, float* __restrict__ out) {
    const int row = blockIdx.x;
    const int t   = threadIdx.x;
    const size_t base = (size_t)row * N;

    const float si = src[row];

    const float4* adj4 = reinterpret_cast<const float4*>(adj + base);
    const float4* dst4 = reinterpret_cast<const float4*>(dst);

    float v[32];
    float lmax = -VERY_SMALL;   // matches fully-masked-row semantics exactly

#pragma unroll
    for (int it = 0; it < 8; ++it) {
        const int idx4 = it * 256 + t;
        float4 av = adj4[idx4];
        float4 dv = dst4[idx4];

        float e0 = si + dv.x; e0 = (e0 > 0.f) ? e0 : NEG_SLOPE * e0;
        float e1 = si + dv.y; e1 = (e1 > 0.f) ? e1 : NEG_SLOPE * e1;
        float e2 = si + dv.z; e2 = (e2 > 0.f) ? e2 : NEG_SLOPE * e2;
        float e3 = si + dv.w; e3 = (e3 > 0.f) ? e3 : NEG_SLOPE * e3;

        float m0 = (av.x > 0.f) ? e0 : -VERY_SMALL;
        float m1 = (av.y > 0.f) ? e1 : -VERY_SMALL;
        float m2 = (av.z > 0.f) ? e2 : -VERY_SMALL;
        float m3 = (av.w > 0.f) ? e3 : -VERY_SMALL;

        v[it*4+0] = m0; v[it*4+1] = m1; v[it*4+2] = m2; v[it*4+3] = m3;
        lmax = fmaxf(lmax, fmaxf(fmaxf(m0, m1), fmaxf(m2, m3)));
    }

    // block max reduce (4 waves)
    __shared__ float sred[4];
    float wm = waveReduceMax(lmax);
    const int wave = t >> 6;
    if ((t & 63) == 0) sred[wave] = wm;
    __syncthreads();
    const float rmax = fmaxf(fmaxf(sred[0], sred[1]), fmaxf(sred[2], sred[3]));
    __syncthreads();   // sred reused below

    // exponentiate in-register, local sum
    float lsum = 0.f;
#pragma unroll
    for (int k = 0; k < 32; ++k) {
        v[k] = __expf(v[k] - rmax);   // masked: exp(-1e12 - rmax) -> 0
        lsum += v[k];
    }

    // block sum reduce
    float wsum = waveReduceSum(lsum);
    if ((t & 63) == 0) sred[wave] = wsum;
    __syncthreads();
    const float rsum = sred[0] + sred[1] + sred[2] + sred[3];
    const float inv = 1.0f / rsum;

    // scale + write
    float4* out4 = reinterpret_cast<float4*>(out + base);
#pragma unroll
    for (int it = 0; it < 8; ++it) {
        const int idx4 = it * 256 + t;
        float4 o;
        o.x = v[it*4+0] * inv;
        o.y = v[it*4+1] * inv;
        o.z = v[it*4+2] * inv;
        o.w = v[it*4+3] * inv;
        out4[idx4] = o;
    }
}

// ---------------------------------------------------------------------------
extern "C" void kernel_launch(void* const* d_in, const int* in_sizes, int n_in,
                              void* d_out, int out_size, void* d_ws, size_t ws_size,
                              hipStream_t stream) {
    const float* h   = (const float*)d_in[0];   // (N, F_IN)
    const float* adj = (const float*)d_in[1];   // (N, N)
    const float* w   = (const float*)d_in[2];   // (F_IN, F_OUT)
    const float* a   = (const float*)d_in[3];   // (2*F_OUT, 1)
    float* out = (float*)d_out;                 // (N, N)

    float* W   = (float*)d_ws;
    float* wsv = W;                 // 128
    float* wdv = W + F_IN;          // 128
    float* src = W + 2 * F_IN;      // N
    float* dst = W + 2 * F_IN + N;  // N

    prep_kernel<<<1, F_IN, 0, stream>>>(w, a, wsv, wdv);
    srcdst_kernel<<<N / 256, 256, 0, stream>>>(h, wsv, wdv, src, dst);
    row_softmax_kernel<<<N, 256, 0, stream>>>(adj, src, dst, out);
}

// Round 4
// 429.618 us; speedup vs baseline: 1.0395x; 1.0395x over previous
//
#include <hip/hip_runtime.h>

#define N       8192
#define F_IN    128
#define F_OUT   64
#define NEG_SLOPE 0.2f
#define VERY_SMALL 1.0e12f

// native vector type — accepted by __builtin_nontemporal_load/store
typedef float fv4 __attribute__((ext_vector_type(4)));

// ---------------------------------------------------------------------------
// K1 (fused prep + src/dst):
//   ws[k] = sum_j w[k][j]*a[j] ; wd[k] = sum_j w[k][j]*a[F_OUT+j]  (in LDS)
//   src[i] = dot(h[i,:], ws) ; dst[i] = dot(h[i,:], wd)
// grid 64 x 128 threads — one row of h per thread, float4 loads.
// ---------------------------------------------------------------------------
__global__ __launch_bounds__(128) void srcdst_kernel(
        const float* __restrict__ h, const float* __restrict__ w,
        const float* __restrict__ a,
        float* __restrict__ src, float* __restrict__ dst) {
    __shared__ float sws[F_IN], swd[F_IN];
    const int t = threadIdx.x;           // 0..127
    {
        float s = 0.f, d = 0.f;
#pragma unroll
        for (int j = 0; j < F_OUT; ++j) {
            float wv = w[t * F_OUT + j];
            s += wv * a[j];
            d += wv * a[F_OUT + j];
        }
        sws[t] = s; swd[t] = d;
    }
    __syncthreads();
    const int i = blockIdx.x * 128 + t;
    const fv4* h4 = reinterpret_cast<const fv4*>(h + (size_t)i * F_IN);
    float s = 0.f, d = 0.f;
#pragma unroll
    for (int k4 = 0; k4 < F_IN / 4; ++k4) {
        fv4 hv = h4[k4];
        s += hv.x * sws[k4*4+0] + hv.y * sws[k4*4+1] + hv.z * sws[k4*4+2] + hv.w * sws[k4*4+3];
        d += hv.x * swd[k4*4+0] + hv.y * swd[k4*4+1] + hv.z * swd[k4*4+2] + hv.w * swd[k4*4+3];
    }
    src[i] = s;
    dst[i] = d;
}

// ---------------------------------------------------------------------------
// K2: masked row softmax, TWO rows per 512-thread block (grid N/2).
// Per thread: 4 float4 per row (16 elems/row), dst loads shared across rows.
// Logits held in registers; nontemporal adj loads / out stores.
// ---------------------------------------------------------------------------
__device__ __forceinline__ float waveReduceMax(float x) {
#pragma unroll
    for (int off = 32; off > 0; off >>= 1) x = fmaxf(x, __shfl_xor(x, off));
    return x;
}
__device__ __forceinline__ float waveReduceSum(float x) {
#pragma unroll
    for (int off = 32; off > 0; off >>= 1) x += __shfl_xor(x, off);
    return x;
}

__global__ __launch_bounds__(512) void row_softmax_kernel(
        const float* __restrict__ adj, const float* __restrict__ src,
        const float* __restrict__ dst, float* __restrict__ out) {
    const int r0 = blockIdx.x * 2;
    const int t  = threadIdx.x;          // 0..511
    const float s0 = src[r0];
    const float s1 = src[r0 + 1];

    const fv4* adjA = reinterpret_cast<const fv4*>(adj + (size_t)r0 * N);
    const fv4* adjB = reinterpret_cast<const fv4*>(adj + (size_t)(r0 + 1) * N);
    const fv4* dst4 = reinterpret_cast<const fv4*>(dst);

    float v0[16], v1[16];
    float lm0 = -VERY_SMALL, lm1 = -VERY_SMALL;

#pragma unroll
    for (int it = 0; it < 4; ++it) {
        const int idx4 = it * 512 + t;
        fv4 dv = dst4[idx4];                               // cached (L1/L2)
        fv4 aA = __builtin_nontemporal_load(&adjA[idx4]);  // streaming
        fv4 aB = __builtin_nontemporal_load(&adjB[idx4]);

        float e;
        e = s0 + dv.x; e = (e > 0.f) ? e : NEG_SLOPE * e; float a0 = (aA.x > 0.f) ? e : -VERY_SMALL;
        e = s0 + dv.y; e = (e > 0.f) ? e : NEG_SLOPE * e; float a1 = (aA.y > 0.f) ? e : -VERY_SMALL;
        e = s0 + dv.z; e = (e > 0.f) ? e : NEG_SLOPE * e; float a2 = (aA.z > 0.f) ? e : -VERY_SMALL;
        e = s0 + dv.w; e = (e > 0.f) ? e : NEG_SLOPE * e; float a3 = (aA.w > 0.f) ? e : -VERY_SMALL;
        e = s1 + dv.x; e = (e > 0.f) ? e : NEG_SLOPE * e; float b0 = (aB.x > 0.f) ? e : -VERY_SMALL;
        e = s1 + dv.y; e = (e > 0.f) ? e : NEG_SLOPE * e; float b1 = (aB.y > 0.f) ? e : -VERY_SMALL;
        e = s1 + dv.z; e = (e > 0.f) ? e : NEG_SLOPE * e; float b2 = (aB.z > 0.f) ? e : -VERY_SMALL;
        e = s1 + dv.w; e = (e > 0.f) ? e : NEG_SLOPE * e; float b3 = (aB.w > 0.f) ? e : -VERY_SMALL;

        v0[it*4+0] = a0; v0[it*4+1] = a1; v0[it*4+2] = a2; v0[it*4+3] = a3;
        v1[it*4+0] = b0; v1[it*4+1] = b1; v1[it*4+2] = b2; v1[it*4+3] = b3;
        lm0 = fmaxf(lm0, fmaxf(fmaxf(a0, a1), fmaxf(a2, a3)));
        lm1 = fmaxf(lm1, fmaxf(fmaxf(b0, b1), fmaxf(b2, b3)));
    }

    // block max reduce (8 waves)
    __shared__ float smax[2][8], ssum[2][8];
    const int wave = t >> 6;
    float wm0 = waveReduceMax(lm0);
    float wm1 = waveReduceMax(lm1);
    if ((t & 63) == 0) { smax[0][wave] = wm0; smax[1][wave] = wm1; }
    __syncthreads();
    float rmax0 = smax[0][0], rmax1 = smax[1][0];
#pragma unroll
    for (int k = 1; k < 8; ++k) {
        rmax0 = fmaxf(rmax0, smax[0][k]);
        rmax1 = fmaxf(rmax1, smax[1][k]);
    }

    // exponentiate in-register, local sums
    float ls0 = 0.f, ls1 = 0.f;
#pragma unroll
    for (int k = 0; k < 16; ++k) {
        v0[k] = __expf(v0[k] - rmax0); ls0 += v0[k];
        v1[k] = __expf(v1[k] - rmax1); ls1 += v1[k];
    }

    // block sum reduce
    float ws0 = waveReduceSum(ls0);
    float ws1 = waveReduceSum(ls1);
    if ((t & 63) == 0) { ssum[0][wave] = ws0; ssum[1][wave] = ws1; }
    __syncthreads();
    float rs0 = ssum[0][0], rs1 = ssum[1][0];
#pragma unroll
    for (int k = 1; k < 8; ++k) { rs0 += ssum[0][k]; rs1 += ssum[1][k]; }
    const float inv0 = 1.0f / rs0;
    const float inv1 = 1.0f / rs1;

    // scale + nontemporal write
    fv4* outA = reinterpret_cast<fv4*>(out + (size_t)r0 * N);
    fv4* outB = reinterpret_cast<fv4*>(out + (size_t)(r0 + 1) * N);
#pragma unroll
    for (int it = 0; it < 4; ++it) {
        const int idx4 = it * 512 + t;
        fv4 oA, oB;
        oA.x = v0[it*4+0] * inv0; oA.y = v0[it*4+1] * inv0;
        oA.z = v0[it*4+2] * inv0; oA.w = v0[it*4+3] * inv0;
        oB.x = v1[it*4+0] * inv1; oB.y = v1[it*4+1] * inv1;
        oB.z = v1[it*4+2] * inv1; oB.w = v1[it*4+3] * inv1;
        __builtin_nontemporal_store(oA, &outA[idx4]);
        __builtin_nontemporal_store(oB, &outB[idx4]);
    }
}

// ---------------------------------------------------------------------------
extern "C" void kernel_launch(void* const* d_in, const int* in_sizes, int n_in,
                              void* d_out, int out_size, void* d_ws, size_t ws_size,
                              hipStream_t stream) {
    const float* h   = (const float*)d_in[0];   // (N, F_IN)
    const float* adj = (const float*)d_in[1];   // (N, N)
    const float* w   = (const float*)d_in[2];   // (F_IN, F_OUT)
    const float* a   = (const float*)d_in[3];   // (2*F_OUT, 1)
    float* out = (float*)d_out;                 // (N, N)

    float* W   = (float*)d_ws;
    float* src = W;          // N floats
    float* dst = W + N;      // N floats

    srcdst_kernel<<<N / 128, 128, 0, stream>>>(h, w, a, src, dst);
    row_softmax_kernel<<<N / 2, 512, 0, stream>>>(adj, src, dst, out);
}